// Round 6
// baseline (1824.439 us; speedup 1.0000x reference)
//
#include <hip/hip_runtime.h>
#include <math.h>

// Problem constants
#define B 128
#define T 256
#define D 512
#define H 1024
#define KTOT 1536   // D + H
#define N4 4096     // 4*H

// h exchange: tag-carrying 8B chunks {tag(4B) | h1,h0 (2x bf16)}.
// 2 ping-pong slabs of 256 regions x 256 chunks (512 KB each).
// Safety: producer X stores h(t+2) over h(t) only after X consumed ALL of
// h(t+1); every producer of h(t+1) consumed h(t) first (all-to-all read set),
// so all readers of X's chunk(t) are done. Tags strictly increase -> no ABA.
// Poison 0xAAAAAAAA never equals a tag in 1..256.
#define HSLAB ((size_t)256 * 256)   // u64 per slab

typedef short short8 __attribute__((ext_vector_type(8)));
typedef float f32x16 __attribute__((ext_vector_type(16)));
typedef unsigned int uint4v __attribute__((ext_vector_type(4)));
typedef unsigned long long u64;

__device__ __forceinline__ unsigned short f2bf(float f) {
    unsigned int u = __builtin_bit_cast(unsigned int, f);
    unsigned int r = (u + 0x7fffu + ((u >> 16) & 1u)) >> 16;  // RNE
    return (unsigned short)r;
}
__device__ __forceinline__ float bf2f(unsigned short s) {
    unsigned int u = ((unsigned int)s) << 16;
    return __builtin_bit_cast(float, u);
}
__device__ __forceinline__ float sigm(float x) { return 1.f / (1.f + __expf(-x)); }
__device__ __forceinline__ float tanh_fast(float x) {
    return 1.f - 2.f / (1.f + __expf(2.f * x));
}

// x fp32 [B][T][D] -> xb bf16 [T][B][D]
__global__ __launch_bounds__(256) void convert_x(
    const float* __restrict__ x, unsigned short* __restrict__ xb)
{
    int bid = blockIdx.x;          // t*B + b
    int t = bid >> 7;
    int b = bid & 127;
    int d = threadIdx.x * 2;
    const float2 v = *(const float2*)&x[((size_t)b * T + t) * D + d];
    unsigned int packed = (unsigned int)f2bf(v.x) | ((unsigned int)f2bf(v.y) << 16);
    *(unsigned int*)&xb[((size_t)t * B + b) * D + d] = packed;
}

// Wk fp32 [KTOT][4H] -> Wp bf16 [4096][KTOT], permuted: pcol = hc*4 + g
__global__ __launch_bounds__(256) void convert_W(
    const float* __restrict__ Wk, unsigned short* __restrict__ Wp)
{
    __shared__ float tile[32][33];
    int nb = blockIdx.x;   // 0..127
    int kb = blockIdx.y;   // 0..47
    int tx = threadIdx.x & 31;
    int ty = threadIdx.x >> 5;   // 0..7
    #pragma unroll
    for (int i = 0; i < 4; ++i) {
        int k = kb * 32 + ty + i * 8;
        tile[ty + i * 8][tx] = Wk[(size_t)k * N4 + nb * 32 + tx];
    }
    __syncthreads();
    #pragma unroll
    for (int i = 0; i < 4; ++i) {
        int n = nb * 32 + ty + i * 8;
        int pcol = ((n & 1023) << 2) | (n >> 10);
        Wp[(size_t)pcol * KTOT + kb * 32 + tx] = f2bf(tile[tx][ty + i * 8]);
    }
}

// Persistent LSTM. 256 blocks x 256 threads, 1 block/CU.
// h-W in registers (128 VGPR), x-W in LDS (64 KB). One barrier/step (zbuf
// double-buffered). Exchange: tag-fused 8B chunks, fire-and-forget stores,
// self-validating consumer loads with retry. No drain / flags / wcnt / hbuf.
__global__ __launch_bounds__(256, 1) void lstm_persist(
    const unsigned short* __restrict__ xb,     // [T][B][D] bf16
    const unsigned short* __restrict__ Wp,     // [4096][KTOT] bf16 permuted
    const float* __restrict__ bk,              // [4H]
    u64* __restrict__ hs0,                     // slab for even-t stores
    u64* __restrict__ hs1)                     // slab for odd-t stores
{
    __shared__ float zbuf[2][4][64][36];            // dbuf K-quarter partials, 73728 B
    __shared__ __align__(16) unsigned short xw[32768];  // x-W frags, 65536 B

    const int tid  = threadIdx.x;
    const int bi   = blockIdx.x;
    // XCD-clustered mapping (assumes xcd ~ bi&7; wrong -> only perf changes).
    const int rg   = (bi & 7) >> 1;               // row-group: rows [32rg, +32)
    const int cg   = ((bi >> 3) << 1) | (bi & 1); // 0..63: h-cols [16cg, +16)
    const int kq   = tid >> 6;     // wave = K-quarter
    const int lane = tid & 63;
    const int l31  = lane & 31;
    const int lhi  = lane >> 5;    // 0/1

    const int row = rg * 32 + l31;             // A row (m = lane&31)

    // ---- h-W fragments into registers; x-W fragments into LDS ----
    short8 wb[32];   // h chunks j=0..15 x 2 n-tiles
    const unsigned short* wb0 = Wp + (size_t)(cg * 64 + l31) * KTOT + lhi * 8;
    const unsigned short* wb1 = wb0 + (size_t)32 * KTOT;
    #pragma unroll
    for (int j = 0; j < 16; ++j) {
        int k = 512 + (kq * 16 + j) * 16;
        wb[2 * j]     = *(const short8*)(wb0 + k);
        wb[2 * j + 1] = *(const short8*)(wb1 + k);
    }
    #pragma unroll
    for (int j = 0; j < 8; ++j) {
        int k = (kq * 8 + j) * 16;
        *(short8*)&xw[(((kq * 8 + j) * 2 + 0) * 64 + lane) * 8] = *(const short8*)(wb0 + k);
        *(short8*)&xw[(((kq * 8 + j) * 2 + 1) * 64 + lane) * 8] = *(const short8*)(wb1 + k);
    }

    // ---- gate ownership (matches chunk layout so store offset == tid):
    // r = (tid>>1)&31, w = 4*b6 + 2*b7 + b0  (chunk idx = tid, dense 2KB/block)
    const int gr = (tid >> 1) & 31;
    const int gw = ((tid >> 6) & 1) * 4 + ((tid >> 7) & 1) * 2 + (tid & 1);
    float bi_[2], bj_[2], bf_[2], bo_[2];
    #pragma unroll
    for (int u = 0; u < 2; ++u) {
        int hcg = cg * 16 + gw * 2 + u;
        bi_[u] = bk[hcg];
        bj_[u] = bk[H + hcg];
        bf_[u] = bk[2 * H + hcg] + 1.0f;  // forget bias folded
        bo_[u] = bk[3 * H + hcg];
    }
    float cs0 = 0.f, cs1 = 0.f;   // cell state for cols (2gw, 2gw+1) of row gr

    const unsigned short* const xbase = xb + (size_t)row * D + kq * 128 + lhi * 8;
    // consumer: wave kq reads producer blocks cg' = kq*16+j; lane's 4 chunks
    // live at region + j*256 + {0,1,128,129} + lane*2
    const size_t hbase = (size_t)(rg * 64 + kq * 16) * 256 + lane * 2;
    const size_t sbase = (size_t)(rg * 64 + cg) * 256 + tid;

    const f32x16 fz = {0.f,0.f,0.f,0.f,0.f,0.f,0.f,0.f,
                       0.f,0.f,0.f,0.f,0.f,0.f,0.f,0.f};

    __syncthreads();   // xw staged

    for (int t = 0; t < T; ++t) {
        f32x16 a00 = fz, a01 = fz, a10 = fz, a11 = fz;  // [parity][ntile]

        // ---- x loads (cached), then x-MFMAs with LDS weights ----
        const unsigned short* xr = xbase + (size_t)t * (B * D);
        short8 xv[8];
        #pragma unroll
        for (int j = 0; j < 8; ++j)
            xv[j] = *(const short8*)(xr + j * 16);
        #pragma unroll
        for (int j = 0; j < 8; ++j) {
            short8 w0 = *(const short8*)&xw[(((kq * 8 + j) * 2 + 0) * 64 + lane) * 8];
            short8 w1 = *(const short8*)&xw[(((kq * 8 + j) * 2 + 1) * 64 + lane) * 8];
            if (j & 1) {
                a10 = __builtin_amdgcn_mfma_f32_32x32x16_bf16(xv[j], w0, a10, 0, 0, 0);
                a11 = __builtin_amdgcn_mfma_f32_32x32x16_bf16(xv[j], w1, a11, 0, 0, 0);
            } else {
                a00 = __builtin_amdgcn_mfma_f32_32x32x16_bf16(xv[j], w0, a00, 0, 0, 0);
                a01 = __builtin_amdgcn_mfma_f32_32x32x16_bf16(xv[j], w1, a01, 0, 0, 0);
            }
        }

        if (t > 0) {
            // ---- self-validating h loads: tags ride with the data ----
            const u64* hp = ((t & 1) ? hs0 : hs1) + hbase;
            const unsigned want = (unsigned)t;
            short8 pay[16];
            for (;;) {
                unsigned bad = 0;
                #pragma unroll
                for (int j = 0; j < 16; ++j) {
                    const u64* p = hp + j * 256;
                    u64 a = __hip_atomic_load(p,       __ATOMIC_RELAXED, __HIP_MEMORY_SCOPE_AGENT);
                    u64 b = __hip_atomic_load(p + 1,   __ATOMIC_RELAXED, __HIP_MEMORY_SCOPE_AGENT);
                    u64 c = __hip_atomic_load(p + 128, __ATOMIC_RELAXED, __HIP_MEMORY_SCOPE_AGENT);
                    u64 d = __hip_atomic_load(p + 129, __ATOMIC_RELAXED, __HIP_MEMORY_SCOPE_AGENT);
                    uint4v pk = { (unsigned)a, (unsigned)b, (unsigned)c, (unsigned)d };
                    pay[j] = __builtin_bit_cast(short8, pk);
                    bad |= ((unsigned)(a >> 32) ^ want) | ((unsigned)(b >> 32) ^ want)
                         | ((unsigned)(c >> 32) ^ want) | ((unsigned)(d >> 32) ^ want);
                }
                if (!bad) break;
            }
            #pragma unroll
            for (int j = 0; j < 16; ++j) {
                if (j & 1) {
                    a10 = __builtin_amdgcn_mfma_f32_32x32x16_bf16(pay[j], wb[2 * j],     a10, 0, 0, 0);
                    a11 = __builtin_amdgcn_mfma_f32_32x32x16_bf16(pay[j], wb[2 * j + 1], a11, 0, 0, 0);
                } else {
                    a00 = __builtin_amdgcn_mfma_f32_32x32x16_bf16(pay[j], wb[2 * j],     a00, 0, 0, 0);
                    a01 = __builtin_amdgcn_mfma_f32_32x32x16_bf16(pay[j], wb[2 * j + 1], a01, 0, 0, 0);
                }
            }
        }

        f32x16 z0 = a00 + a10;   // ntile 0
        f32x16 z1 = a01 + a11;   // ntile 1

        // ---- K-quarter partials to dbuf'd LDS ----
        // C/D: col=lane&31, row=(reg&3)+8*(reg>>2)+4*lhi
        float (*zb)[64][36] = zbuf[t & 1];
        #pragma unroll
        for (int q = 0; q < 4; ++q) {
            float4 v0 = { z0[4 * q + 0], z0[4 * q + 1], z0[4 * q + 2], z0[4 * q + 3] };
            *(float4*)&zb[kq][l31][lhi * 4 + q * 8] = v0;
            float4 v1 = { z1[4 * q + 0], z1[4 * q + 1], z1[4 * q + 2], z1[4 * q + 3] };
            *(float4*)&zb[kq][32 + l31][lhi * 4 + q * 8] = v1;
        }
        __syncthreads();   // the ONLY barrier per step (dbuf covers t+1 writes)

        // ---- gates: thread owns (row gr, cols 2gw, 2gw+1); pack 8B chunk ----
        unsigned short hb_[2];
        #pragma unroll
        for (int u = 0; u < 2; ++u) {
            int pcb = (gw * 2 + u) * 4;
            float zi = zb[0][pcb + 0][gr] + zb[1][pcb + 0][gr]
                     + zb[2][pcb + 0][gr] + zb[3][pcb + 0][gr] + bi_[u];
            float zj = zb[0][pcb + 1][gr] + zb[1][pcb + 1][gr]
                     + zb[2][pcb + 1][gr] + zb[3][pcb + 1][gr] + bj_[u];
            float zf = zb[0][pcb + 2][gr] + zb[1][pcb + 2][gr]
                     + zb[2][pcb + 2][gr] + zb[3][pcb + 2][gr] + bf_[u];
            float zo = zb[0][pcb + 3][gr] + zb[1][pcb + 3][gr]
                     + zb[2][pcb + 3][gr] + zb[3][pcb + 3][gr] + bo_[u];
            float& cc = u ? cs1 : cs0;
            float cn = cc * sigm(zf) + sigm(zi) * tanh_fast(zj);
            cc = cn;
            hb_[u] = f2bf(sigm(zo) * tanh_fast(cn));
        }

        // ---- fire-and-forget tagged store (coalesced: offset == tid) ----
        {
            u64 val = ((u64)(unsigned)(t + 1) << 32)
                    | ((unsigned)hb_[1] << 16) | (unsigned)hb_[0];
            u64* hd = ((t & 1) ? hs1 : hs0) + sbase;
            __hip_atomic_store(hd, val, __ATOMIC_RELAXED, __HIP_MEMORY_SCOPE_AGENT);
        }
    }
}

// out[128][1000] = h(bf16, tagged-chunk slab)[128][1024] @ w[1024][1000] + b
__global__ __launch_bounds__(256) void proj_kernel(
    const u64* __restrict__ hb, const float* __restrict__ w,
    const float* __restrict__ bias, float* __restrict__ out)
{
    int cidx = blockIdx.x * 256 + threadIdx.x;  // 0..1023
    int bg   = blockIdx.y;                      // 0..7 -> 16 rows each
    bool valid = cidx < 1000;
    float acc[16];
    #pragma unroll
    for (int i = 0; i < 16; ++i) acc[i] = 0.f;

    for (int k = 0; k < H; k += 2) {
        float w0 = 0.f, w1 = 0.f;
        if (valid) {
            w0 = w[(size_t)(k + 0) * 1000 + cidx];
            w1 = w[(size_t)(k + 1) * 1000 + cidx];
        }
        int wloc = (k & 15) >> 1;   // colpair 0..7
        #pragma unroll
        for (int i = 0; i < 16; ++i) {
            int row = bg * 16 + i;
            size_t idx = (size_t)((row >> 5) * 64 + (k >> 4)) * 256
                       + (size_t)((wloc >> 1) & 1) * 128
                       + (size_t)((wloc >> 2) * 32 + (row & 31)) * 2
                       + (wloc & 1);
            unsigned lo = (unsigned)hb[idx];
            acc[i] += bf2f((unsigned short)(lo & 0xffff)) * w0
                    + bf2f((unsigned short)(lo >> 16)) * w1;
        }
    }
    if (valid) {
        #pragma unroll
        for (int i = 0; i < 16; ++i)
            out[(size_t)(bg * 16 + i) * 1000 + cidx] = acc[i] + bias[cidx];
    }
}

extern "C" void kernel_launch(void* const* d_in, const int* in_sizes, int n_in,
                              void* d_out, int out_size, void* d_ws, size_t ws_size,
                              hipStream_t stream) {
    const float* x  = (const float*)d_in[0];  // [B,T,D]
    const float* Wk = (const float*)d_in[1];  // [D+H, 4H]
    const float* bk = (const float*)d_in[2];  // [4H]
    const float* w  = (const float*)d_in[3];  // [H, C]
    const float* b  = (const float*)d_in[4];  // [C]
    float* out = (float*)d_out;               // [B, C]

    char* p = (char*)d_ws;
    unsigned short* xb = (unsigned short*)p;  p += (size_t)B * T * D * 2;   // 33.55 MB
    unsigned short* Wp = (unsigned short*)p;  p += (size_t)N4 * KTOT * 2;   // 12.58 MB
    u64* hs0 = (u64*)p;  p += HSLAB * 8;                                    // 512 KB
    u64* hs1 = (u64*)p;  p += HSLAB * 8;                                    // 512 KB

    // No flag memset needed: tags are fused into the data chunks and the
    // workspace's 0xAA re-poison (0xAAAAAAAA) never matches a tag in 1..256.

    convert_x<<<dim3(T * B), dim3(256), 0, stream>>>(x, xb);
    convert_W<<<dim3(N4 / 32, KTOT / 32), dim3(256), 0, stream>>>(Wk, Wp);

    lstm_persist<<<dim3(256), dim3(256), 0, stream>>>(xb, Wp, bk, hs0, hs1);

    // t=255 (odd) stored into hs1 -> final hidden state (tagged chunks)
    proj_kernel<<<dim3(4, 8), dim3(256), 0, stream>>>(hs1, w, b, out);
}

// Round 7
// 1323.910 us; speedup vs baseline: 1.3781x; 1.3781x over previous
//
#include <hip/hip_runtime.h>
#include <math.h>

// Problem constants
#define B 128
#define T 256
#define D 512
#define H 1024
#define KTOT 1536   // D + H
#define N4 4096     // 4*H

// h ring: one slab per step, 4KB skew. Slab layout is BLOCK-MAJOR:
// [rg*64+cg][r32][c16] — each producer block owns a dense 1KB region
// (full-line writes, no amplification; consumers read dense 1KB chunks).
#define HSTRIDE ((size_t)B * H + 2048)   // in ushorts; 266240 B per step

typedef short short8 __attribute__((ext_vector_type(8)));
typedef float f32x16 __attribute__((ext_vector_type(16)));

__device__ __forceinline__ unsigned short f2bf(float f) {
    unsigned int u = __builtin_bit_cast(unsigned int, f);
    unsigned int r = (u + 0x7fffu + ((u >> 16) & 1u)) >> 16;  // RNE
    return (unsigned short)r;
}
__device__ __forceinline__ float bf2f(unsigned short s) {
    unsigned int u = ((unsigned int)s) << 16;
    return __builtin_bit_cast(float, u);
}
__device__ __forceinline__ float sigm(float x) { return 1.f / (1.f + __expf(-x)); }
__device__ __forceinline__ float tanh_fast(float x) {
    return 1.f - 2.f / (1.f + __expf(2.f * x));
}

// x fp32 [B][T][D] -> xb bf16 [T][B][D]
__global__ __launch_bounds__(256) void convert_x(
    const float* __restrict__ x, unsigned short* __restrict__ xb)
{
    int bid = blockIdx.x;          // t*B + b
    int t = bid >> 7;
    int b = bid & 127;
    int d = threadIdx.x * 2;
    const float2 v = *(const float2*)&x[((size_t)b * T + t) * D + d];
    unsigned int packed = (unsigned int)f2bf(v.x) | ((unsigned int)f2bf(v.y) << 16);
    *(unsigned int*)&xb[((size_t)t * B + b) * D + d] = packed;
}

// Wk fp32 [KTOT][4H] -> Wp bf16 [4096][KTOT], permuted: pcol = hc*4 + g
__global__ __launch_bounds__(256) void convert_W(
    const float* __restrict__ Wk, unsigned short* __restrict__ Wp)
{
    __shared__ float tile[32][33];
    int nb = blockIdx.x;   // 0..127
    int kb = blockIdx.y;   // 0..47
    int tx = threadIdx.x & 31;
    int ty = threadIdx.x >> 5;   // 0..7
    #pragma unroll
    for (int i = 0; i < 4; ++i) {
        int k = kb * 32 + ty + i * 8;
        tile[ty + i * 8][tx] = Wk[(size_t)k * N4 + nb * 32 + tx];
    }
    __syncthreads();
    #pragma unroll
    for (int i = 0; i < 4; ++i) {
        int n = nb * 32 + ty + i * 8;
        int pcol = ((n & 1023) << 2) | (n >> 10);
        Wp[(size_t)pcol * KTOT + kb * 32 + tx] = f2bf(tile[tx][ty + i * 8]);
    }
}

// Persistent LSTM. 256 blocks x 256 threads, 1 block/CU, W in registers.
// Round-5 structure (cached h loads, block-major slab, hbuf, 2 barriers,
// XCD-clustered remap) + per-wave flags (no wcnt RMW; earlier publish) +
// per-chunk gated h-load issue with x-MFMAs interleaved into wait slots.
__global__ __launch_bounds__(256, 1) void lstm_persist(
    const unsigned short* __restrict__ xb,     // [T][B][D] bf16
    const unsigned short* __restrict__ Wp,     // [4096][KTOT] bf16 permuted
    const float* __restrict__ bk,              // [4H]
    unsigned short* __restrict__ hring,        // [T][HSTRIDE] bf16 ring, block-major
    unsigned int* __restrict__ arr)            // [4 rg][64 cg][4 w] flags (zeroed)
{
    __shared__ float zbuf[4][64][36];              // K-quarter partials, 36864 B
    __shared__ unsigned short hbuf[32][20];        // 1280 B

    const int tid  = threadIdx.x;
    const int bi   = blockIdx.x;
    // XCD-clustered mapping: rg lives on an XCD pair (assumes xcd ~ bi&7;
    // wrong assumption -> random placement, correctness unaffected).
    const int rg   = (bi & 7) >> 1;               // row-group: rows [32rg, +32)
    const int cg   = ((bi >> 3) << 1) | (bi & 1); // 0..63: h-cols [16cg, +16)
    const int kq   = tid >> 6;     // wave = K-quarter
    const int lane = tid & 63;
    const int l31  = lane & 31;
    const int lhi  = lane >> 5;    // 0/1

    const int row = rg * 32 + l31;             // A row (m = lane&31)

    // ---- W fragments into registers, forever ----
    // wave kq covers x k-cols [kq*128,+128) and h k-cols [kq*256,+256),
    // two n-tiles (pcols cg*64 + nt*32 + l31).
    short8 wb[48];   // [x j=0..7 | h j=0..15] x 2 n-tiles
    const unsigned short* wb0 = Wp + (size_t)(cg * 64 + l31) * KTOT + lhi * 8;
    const unsigned short* wb1 = wb0 + (size_t)32 * KTOT;
    #pragma unroll
    for (int j = 0; j < 8; ++j) {
        int k = (kq * 8 + j) * 16;
        wb[2 * j]     = *(const short8*)(wb0 + k);
        wb[2 * j + 1] = *(const short8*)(wb1 + k);
    }
    #pragma unroll
    for (int j = 0; j < 16; ++j) {
        int k = 512 + (kq * 16 + j) * 16;
        wb[16 + 2 * j]     = *(const short8*)(wb0 + k);
        wb[16 + 2 * j + 1] = *(const short8*)(wb1 + k);
    }

    // ---- bias preload for this thread's two gate elements (round-3 map) ----
    float bi_[2], bj_[2], bf_[2], bo_[2];
    #pragma unroll
    for (int u = 0; u < 2; ++u) {
        int e   = tid + u * 256;
        int hcl = e >> 5;                 // 0..15
        int hcg = cg * 16 + hcl;
        bi_[u] = bk[hcg];
        bj_[u] = bk[H + hcg];
        bf_[u] = bk[2 * H + hcg] + 1.0f;  // forget bias folded
        bo_[u] = bk[3 * H + hcg];
    }
    float cs0 = 0.f, cs1 = 0.f;   // cell state, persistent in registers

    // flags layout: arr[rg*256 + cg*4 + w]. Consumer wave kq lane l polls
    // flag of (producer block 16kq + (l>>2), wave l&3) = arr[rg*256+64kq+l].
    const unsigned int* const fpoll = arr + rg * 256 + kq * 64 + lane;
    unsigned int* const fmine = arr + rg * 256 + cg * 4 + kq;   // own wave flag
    const unsigned short* const xbase = xb + (size_t)row * D + kq * 128 + lhi * 8;
    // consumer chunk-j base within a slab: producer block (rg, kq*16+j)'s
    // dense region + this lane's (r32=l31, c16=lhi*8) fragment.
    const size_t hoff = (size_t)(rg * 64 + kq * 16) * 512 + l31 * 16 + lhi * 8;
    // producer store base (uint index): dense 1KB region, offset = tid
    const size_t soff = (size_t)(rg * 64 + cg) * 256;

    const f32x16 fz = {0.f,0.f,0.f,0.f,0.f,0.f,0.f,0.f,
                       0.f,0.f,0.f,0.f,0.f,0.f,0.f,0.f};

    for (int t = 0; t < T; ++t) {
        f32x16 a00 = fz, a01 = fz, a10 = fz, a11 = fz;  // [parity][ntile]

        // ---- issue x loads first (no h dependency; fill under wait shadow) ----
        const unsigned short* xr = xbase + (size_t)t * (B * D);
        short8 xv[8];
        #pragma unroll
        for (int j = 0; j < 8; ++j)
            xv[j] = *(const short8*)(xr + j * 16);

        if (t > 0) {
            // ---- per-chunk gated h-load issue with x-MFMA fill-in ----
            // lane l tracks flag (block 16kq+(l>>2), wave l&3); ballot gives a
            // 64-bit readiness map; chunk j ready iff nibble j == 0xF.
            unsigned fv = __hip_atomic_load(fpoll, __ATOMIC_RELAXED,
                                            __HIP_MEMORY_SCOPE_AGENT);
            unsigned long long rb = __ballot(fv >= (unsigned)t);
            const unsigned short* hp = hring + (size_t)(t - 1) * HSTRIDE + hoff;
            short8 hv[16];
            #pragma unroll
            for (int j = 0; j < 16; ++j) {
                while (((rb >> (4 * j)) & 0xFull) != 0xFull) {
                    fv = __hip_atomic_load(fpoll, __ATOMIC_RELAXED,
                                           __HIP_MEMORY_SCOPE_AGENT);
                    rb = __ballot(fv >= (unsigned)t);
                }
                asm volatile("" ::: "memory");   // no hoisting loads above wait
                hv[j] = *(const short8*)(hp + j * 512);
                if (j < 8) {
                    // x-MFMA pair j executes under the wait/fill shadow
                    if (j & 1) {
                        a10 = __builtin_amdgcn_mfma_f32_32x32x16_bf16(xv[j], wb[2 * j],     a10, 0, 0, 0);
                        a11 = __builtin_amdgcn_mfma_f32_32x32x16_bf16(xv[j], wb[2 * j + 1], a11, 0, 0, 0);
                    } else {
                        a00 = __builtin_amdgcn_mfma_f32_32x32x16_bf16(xv[j], wb[2 * j],     a00, 0, 0, 0);
                        a01 = __builtin_amdgcn_mfma_f32_32x32x16_bf16(xv[j], wb[2 * j + 1], a01, 0, 0, 0);
                    }
                }
            }
            #pragma unroll
            for (int j = 0; j < 16; ++j) {
                if (j & 1) {
                    a10 = __builtin_amdgcn_mfma_f32_32x32x16_bf16(hv[j], wb[16 + 2 * j],     a10, 0, 0, 0);
                    a11 = __builtin_amdgcn_mfma_f32_32x32x16_bf16(hv[j], wb[16 + 2 * j + 1], a11, 0, 0, 0);
                } else {
                    a00 = __builtin_amdgcn_mfma_f32_32x32x16_bf16(hv[j], wb[16 + 2 * j],     a00, 0, 0, 0);
                    a01 = __builtin_amdgcn_mfma_f32_32x32x16_bf16(hv[j], wb[16 + 2 * j + 1], a01, 0, 0, 0);
                }
            }
        } else {
            #pragma unroll
            for (int j = 0; j < 8; ++j) {
                if (j & 1) {
                    a10 = __builtin_amdgcn_mfma_f32_32x32x16_bf16(xv[j], wb[2 * j],     a10, 0, 0, 0);
                    a11 = __builtin_amdgcn_mfma_f32_32x32x16_bf16(xv[j], wb[2 * j + 1], a11, 0, 0, 0);
                } else {
                    a00 = __builtin_amdgcn_mfma_f32_32x32x16_bf16(xv[j], wb[2 * j],     a00, 0, 0, 0);
                    a01 = __builtin_amdgcn_mfma_f32_32x32x16_bf16(xv[j], wb[2 * j + 1], a01, 0, 0, 0);
                }
            }
        }

        f32x16 z0 = a00 + a10;   // ntile 0
        f32x16 z1 = a01 + a11;   // ntile 1

        // ---- K-quarter partials to LDS. C/D: col=lane&31, row=(reg&3)+8*(reg>>2)+4*lhi
        #pragma unroll
        for (int q = 0; q < 4; ++q) {
            float4 v0 = { z0[4 * q + 0], z0[4 * q + 1], z0[4 * q + 2], z0[4 * q + 3] };
            *(float4*)&zbuf[kq][l31][lhi * 4 + q * 8] = v0;
            float4 v1 = { z1[4 * q + 0], z1[4 * q + 1], z1[4 * q + 2], z1[4 * q + 3] };
            *(float4*)&zbuf[kq][32 + l31][lhi * 4 + q * 8] = v1;
        }
        __syncthreads();   // zbuf complete (also fences hbuf(t-1) reads vs writes)

        // ---- gates: 512 h-elems/block, 2 per thread; results to hbuf (LDS) ----
        #pragma unroll
        for (int u = 0; u < 2; ++u) {
            int e   = tid + u * 256;
            int r   = e & 31;
            int hcl = e >> 5;
            int pcb = hcl * 4;
            float zi = zbuf[0][pcb + 0][r] + zbuf[1][pcb + 0][r]
                     + zbuf[2][pcb + 0][r] + zbuf[3][pcb + 0][r] + bi_[u];
            float zj = zbuf[0][pcb + 1][r] + zbuf[1][pcb + 1][r]
                     + zbuf[2][pcb + 1][r] + zbuf[3][pcb + 1][r] + bj_[u];
            float zf = zbuf[0][pcb + 2][r] + zbuf[1][pcb + 2][r]
                     + zbuf[2][pcb + 2][r] + zbuf[3][pcb + 2][r] + bf_[u];
            float zo = zbuf[0][pcb + 3][r] + zbuf[1][pcb + 3][r]
                     + zbuf[2][pcb + 3][r] + zbuf[3][pcb + 3][r] + bo_[u];
            float& cc = u ? cs1 : cs0;
            float cn = cc * sigm(zf) + sigm(zi) * tanh_fast(zj);
            cc = cn;
            float hn = sigm(zo) * tanh_fast(cn);
            hbuf[r][hcl] = f2bf(hn);
        }
        __syncthreads();   // hbuf complete (also fences zbuf(t) reads vs t+1 writes)

        // ---- dense h-store: 256 consecutive uints (1KB region, full lines) ----
        {
            int r  = tid >> 3;
            int cp = tid & 7;
            unsigned int v = *(const unsigned int*)&hbuf[r][cp * 2];
            unsigned int* hdst = (unsigned int*)(hring + (size_t)t * HSTRIDE);
            __hip_atomic_store(&hdst[soff + tid], v,
                               __ATOMIC_RELAXED, __HIP_MEMORY_SCOPE_AGENT);
        }
        if (t != T - 1) {
            // per-wave drain (4 full lines), then own flag. No wcnt, no barrier.
            asm volatile("s_waitcnt vmcnt(0)" ::: "memory");
            if (lane == 0)
                __hip_atomic_store(fmine, (unsigned)(t + 1),
                                   __ATOMIC_RELAXED, __HIP_MEMORY_SCOPE_AGENT);
        }
    }
}

// out[128][1000] = h(bf16, block-major slab)[128][1024] @ w[1024][1000] + b
__global__ __launch_bounds__(256) void proj_kernel(
    const unsigned short* __restrict__ hb, const float* __restrict__ w,
    const float* __restrict__ bias, float* __restrict__ out)
{
    int cidx = blockIdx.x * 256 + threadIdx.x;  // 0..1023
    int bg   = blockIdx.y;                      // 0..7 -> 16 rows each
    bool valid = cidx < 1000;
    float acc[16];
    #pragma unroll
    for (int i = 0; i < 16; ++i) acc[i] = 0.f;

    for (int k = 0; k < H; k += 4) {
        float w0 = 0.f, w1 = 0.f, w2 = 0.f, w3 = 0.f;
        if (valid) {
            w0 = w[(size_t)(k + 0) * 1000 + cidx];
            w1 = w[(size_t)(k + 1) * 1000 + cidx];
            w2 = w[(size_t)(k + 2) * 1000 + cidx];
            w3 = w[(size_t)(k + 3) * 1000 + cidx];
        }
        #pragma unroll
        for (int i = 0; i < 16; ++i) {
            int row = bg * 16 + i;
            // block-major: [ (row>>5)*64 + (k>>4) ][ row&31 ][ k&15 ]
            size_t a = (size_t)((row >> 5) * 64 + (k >> 4)) * 512
                     + (size_t)(row & 31) * 16 + (k & 15);
            ushort4 hv = *(const ushort4*)&hb[a];
            acc[i] += bf2f(hv.x) * w0 + bf2f(hv.y) * w1
                    + bf2f(hv.z) * w2 + bf2f(hv.w) * w3;
        }
    }
    if (valid) {
        #pragma unroll
        for (int i = 0; i < 16; ++i)
            out[(size_t)(bg * 16 + i) * 1000 + cidx] = acc[i] + bias[cidx];
    }
}

extern "C" void kernel_launch(void* const* d_in, const int* in_sizes, int n_in,
                              void* d_out, int out_size, void* d_ws, size_t ws_size,
                              hipStream_t stream) {
    const float* x  = (const float*)d_in[0];  // [B,T,D]
    const float* Wk = (const float*)d_in[1];  // [D+H, 4H]
    const float* bk = (const float*)d_in[2];  // [4H]
    const float* w  = (const float*)d_in[3];  // [H, C]
    const float* b  = (const float*)d_in[4];  // [C]
    float* out = (float*)d_out;               // [B, C]

    char* p = (char*)d_ws;
    unsigned short* xb = (unsigned short*)p;  p += (size_t)B * T * D * 2;   // 33.55 MB
    unsigned short* Wp = (unsigned short*)p;  p += (size_t)N4 * KTOT * 2;   // 12.58 MB
    unsigned short* hr = (unsigned short*)p;  p += HSTRIDE * T * 2;         // 68.16 MB
    unsigned int*   ar = (unsigned int*)p;    p += 4 * 64 * 4 * 4;          // 4 KB flags

    // flags must start zeroed (ws re-poisoned 0xAA before every timed call;
    // 0xAAAAAAAA would read as "ready").
    hipMemsetAsync(ar, 0, 4 * 64 * 4 * 4, stream);

    convert_x<<<dim3(T * B), dim3(256), 0, stream>>>(x, xb);
    convert_W<<<dim3(N4 / 32, KTOT / 32), dim3(256), 0, stream>>>(Wk, Wp);

    lstm_persist<<<dim3(256), dim3(256), 0, stream>>>(xb, Wp, bk, hr, ar);

    // final hidden state is the t=255 slab (block-major layout)
    proj_kernel<<<dim3(4, 8), dim3(256), 0, stream>>>(hr + (size_t)(T - 1) * HSTRIDE,
                                                      w, b, out);
}